// Round 8
// baseline (1078.790 us; speedup 1.0000x reference)
//
#include <hip/hip_runtime.h>
#include <stdint.h>
#include <stddef.h>

// Problem: out[b,a,o] = sum_{i,j} h0[b,a,i] h1[b,a,j] T[a,i,j,o], h=concat(x,1)
// GEMM form: C[b,o] += G[b,k]*Tb[a,k,o]; main k=j*128+i (i,j<128); k=16384+c:
// G=h1[c]; k=16512+c: G=h0[c]; k=16640: G=1. 261 K-tiles of 64.
#define NA     4
#define DDIM   128
#define OUTD   128
#define BM     128
#define BN     128
#define NTILES 261
#define TILE_B 16384          // BN * 64 * 2B
#define OUT_ELEMS (4096 * NA * OUTD)   // 2,097,152 f32

typedef _Float16 f16;
typedef __attribute__((ext_vector_type(8)))  _Float16 f16x8;
typedef __attribute__((ext_vector_type(4)))  float    f32x4;
typedef __attribute__((ext_vector_type(16))) float    f32x16;

static const size_t TB_BYTES = (size_t)NA * NTILES * TILE_B;           // 17,104,896
static const size_t WS4 = TB_BYTES + (size_t)4 * OUT_ELEMS * 4;        // ~50.7 MB
static const size_t WS8 = TB_BYTES + (size_t)8 * OUT_ELEMS * 4;        // ~84.2 MB

// ---------------------------------------------------------------------------
// Prep: T f32 -> Tb f16, per (a,tile) a 16KB image; unit v = w*128+col
// (w=0..7) holds k = tile*64 + w*8 + e at output-col `col`.
// ---------------------------------------------------------------------------
__global__ __launch_bounds__(256) void prep_kernel(const float* __restrict__ T,
                                                   f16* __restrict__ Tb) {
    int blk  = blockIdx.x;            // a*NTILES + tile
    int a    = blk / NTILES;
    int tile = blk - a * NTILES;
    int t    = threadIdx.x;
    f16* base = Tb + (size_t)blk * (TILE_B / 2);
    #pragma unroll
    for (int u = 0; u < 4; ++u) {
        int v   = t + u * 256;
        int w   = v >> 7;
        int col = v & 127;
        f16x8 ov;
        #pragma unroll
        for (int e = 0; e < 8; ++e) {
            int k = tile * 64 + w * 8 + e;
            int i = -1, j = 0;
            if (k < 16384)       { i = k & 127;   j = k >> 7;    }
            else if (k < 16512)  { i = 128;       j = k - 16384; }
            else if (k < 16640)  { i = k - 16512; j = 128;       }
            else if (k == 16640) { i = 128;       j = 128;       }
            float val = 0.f;
            if (i >= 0) val = T[(((size_t)a * 129 + i) * 129 + j) * 128 + col];
            ov[e] = (f16)val;
        }
        *(f16x8*)(base + (size_t)v * 8) = ov;
    }
}

__device__ __forceinline__ f16x8 pack_f16x8(f32x4 a, f32x4 b) {
    f16x8 h;
    #pragma unroll
    for (int e = 0; e < 4; ++e) { h[e] = (f16)a[e]; h[e + 4] = (f16)b[e]; }
    return h;
}

// ---------------------------------------------------------------------------
// GEMM: BM=128 x BN=128, 4 waves (1M x 4N), wave = 128 rows x 32 cols, fm=4
// (fm>=4 keeps per-CU MFMA:L1 ratio >= 2:1; waves read DISJOINT B columns ->
// amplification 1x). B direct global->reg, register double buffer, no
// barriers in the loop. NKS = K-split ways: 8 -> 1024 blocks = 4 blocks/CU =
// 4 waves/SIMD (the round-8 change); 4 -> 512 blocks (round-6 fallback).
// h1 j-window from 32KB LDS (full 128 j's, also serves correction tiles).
// ---------------------------------------------------------------------------
template <int NKS, bool ATOMIC>
__global__ __launch_bounds__(256, 4) void gemm_kernel(const float* __restrict__ x0,
                                                      const float* __restrict__ x1,
                                                      const f16* __restrict__ Tb,
                                                      float* __restrict__ dst) {
    constexpr int NT = 256 / NKS;            // main tiles per ks (64 or 32)
    __shared__ __align__(16) f16 h1t[128 * 128];  // 32KB: h1t[j*128+row]

    int bid  = blockIdx.x;
    int xcd  = bid & 7, idx = bid >> 3;
    int pair = xcd * (NKS / 2) + (idx >> 5); // (a,ks) pairs contiguous per XCD
    int mt   = idx & 31;
    int a    = pair & 3;
    int ks   = pair >> 2;

    int t    = threadIdx.x;
    int lane = t & 63, wn = t >> 6;          // 4 waves = 4 disjoint N-column sets
    int l31  = lane & 31, hi = lane >> 5;
    int b0   = mt * BM;

    const char* tbb = (const char*)Tb + (size_t)a * NTILES * TILE_B;
    int ncorr;
    if (NKS == 4) ncorr = (ks == 1) ? 2 : 1;
    else          ncorr = (ks < 5) ? 1 : 0;
    int nt = NT + ncorr;

    // ---- one-time h1 full window -> LDS (transposed, f16) ----
    {
        int row = t & 127, hs = t >> 7;
        const float* x1r = x1 + ((size_t)(b0 + row) * NA + a) * DDIM;
        #pragma unroll
        for (int q = hs * 16; q < hs * 16 + 16; ++q) {
            f32x4 v = *(const f32x4*)(x1r + q * 4);
            #pragma unroll
            for (int e = 0; e < 4; ++e)
                h1t[(q * 4 + e) * 128 + row] = (f16)v[e];
        }
    }
    // ---- one-time h0 -> registers (4 rows/lane, windows split by hi) ----
    f16x8 h0reg[4][2];  // [fm][half]: packed later as 8 windows? keep [4][2] no..
    // (kept as flat 8-window layout per fm via two arrays to stay static)
    f16x8 h0w[8];       // h0w[par*4+kk] belongs to... need per-fm! -> use 4x8:
    (void)h0reg; (void)h0w;
    f16x8 h0r[4][8];
    #pragma unroll
    for (int fm = 0; fm < 4; ++fm) {
        int row = b0 + fm * 32 + l31;
        const float* x0r = x0 + ((size_t)row * NA + a) * DDIM;
        #pragma unroll
        for (int w = 0; w < 8; ++w) {
            int wf = 2 * w + hi;
            h0r[fm][w] = pack_f16x8(*(const f32x4*)(x0r + wf * 8),
                                    *(const f32x4*)(x0r + wf * 8 + 4));
        }
    }
    __syncthreads();   // h1t visible; only barrier in the kernel

    // per-lane B pointer (fragment layout == prep global layout)
    const char* bp = tbb + (size_t)(ks * NT) * TILE_B + hi * 2048 + (wn * 32 + l31) * 16;

    f16x8 bA[4], bB[4];
    #pragma unroll
    for (int kk = 0; kk < 4; ++kk) bA[kk] = *(const f16x8*)(bp + kk * 4096);
    #pragma unroll
    for (int kk = 0; kk < 4; ++kk) bB[kk] = *(const f16x8*)(bp + TILE_B + kk * 4096);

    f32x16 acc[4];
    #pragma unroll
    for (int i = 0; i < 4; ++i) acc[i] = (f32x16)0.f;

    // ---- main loop: NT tiles, barrier-free, register double buffer ----
    #pragma unroll 1
    for (int p = 0; p < NT / 2; ++p) {
        f16 h1v[4];
        #pragma unroll
        for (int fm = 0; fm < 4; ++fm)
            h1v[fm] = h1t[(ks * (NT / 2) + p) * 128 + fm * 32 + l31];

        // tile 2p (i-half 0): windows h0r[fm][kk]
        #pragma unroll
        for (int kk = 0; kk < 4; ++kk) {
            #pragma unroll
            for (int fm = 0; fm < 4; ++fm) {
                f16x8 af = h0r[fm][kk] * h1v[fm];
                acc[fm] = __builtin_amdgcn_mfma_f32_32x32x16_f16(af, bA[kk], acc[fm], 0, 0, 0);
            }
        }
        {   int nxt = 2 * p + 2; if (nxt > NT - 1) nxt = NT - 1;
            const char* q = bp + (size_t)nxt * TILE_B;
            #pragma unroll
            for (int kk = 0; kk < 4; ++kk) bA[kk] = *(const f16x8*)(q + kk * 4096);
        }
        // tile 2p+1 (i-half 1): windows h0r[fm][4+kk]
        #pragma unroll
        for (int kk = 0; kk < 4; ++kk) {
            #pragma unroll
            for (int fm = 0; fm < 4; ++fm) {
                f16x8 af = h0r[fm][4 + kk] * h1v[fm];
                acc[fm] = __builtin_amdgcn_mfma_f32_32x32x16_f16(af, bB[kk], acc[fm], 0, 0, 0);
            }
        }
        {   int nxt = 2 * p + 3; if (nxt > NT - 1) nxt = NT - 1;
            const char* q = bp + (size_t)nxt * TILE_B;
            #pragma unroll
            for (int kk = 0; kk < 4; ++kk) bB[kk] = *(const f16x8*)(q + kk * 4096);
        }
    }

    // ---- correction tail (0-2 tiles, per-ks role) ----
    for (int tt = NT; tt < nt; ++tt) {
        int tile;
        if (NKS == 8) tile = 256 + ks;       // ks0..4 -> 256..260
        else {
            if      (ks == 0) tile = 256;
            else if (ks == 1) tile = (tt == NT) ? 258 : 260;
            else if (ks == 2) tile = 257;
            else              tile = 259;
        }
        const char* q = tbb + (size_t)tile * TILE_B + hi * 2048 + (wn * 32 + l31) * 16;
        f16x8 bt[4];
        #pragma unroll
        for (int kk = 0; kk < 4; ++kk) bt[kk] = *(const f16x8*)(q + kk * 4096);

        #pragma unroll
        for (int kk = 0; kk < 4; ++kk) {
            #pragma unroll
            for (int fm = 0; fm < 4; ++fm) {
                int row = fm * 32 + l31;
                f16x8 af;
                if (tile == 256 || tile == 257) {    // j-corr: G = h1[c]
                    int cb = (tile == 257) ? 64 : 0;
                    #pragma unroll
                    for (int e = 0; e < 8; ++e)
                        af[e] = h1t[(cb + kk * 16 + hi * 8 + e) * 128 + row];
                } else if (tile == 258) {            // i-corr lo: G = h0[c]
                    af = h0r[fm][kk];
                } else if (tile == 259) {            // i-corr hi: G = h0[64+c]
                    af = h0r[fm][4 + kk];
                } else {                             // tile 260: G = 1 at k_local 0
                    af = (f16x8)(f16)0.f;
                    if (kk == 0 && hi == 0) af[0] = (f16)1.f;
                }
                acc[fm] = __builtin_amdgcn_mfma_f32_32x32x16_f16(af, bt[kk], acc[fm], 0, 0, 0);
            }
        }
    }

    // ---- epilogue: C/D 32x32 layout col=lane&31, row=(r&3)+8*(r>>2)+4*hi ----
    float* base = ATOMIC ? dst : dst + (size_t)ks * OUT_ELEMS;
    #pragma unroll
    for (int fm = 0; fm < 4; ++fm)
        #pragma unroll
        for (int r = 0; r < 16; ++r) {
            int orow = b0 + fm * 32 + (r & 3) + 8 * (r >> 2) + 4 * hi;
            int ocol = wn * 32 + l31;
            size_t off = ((size_t)orow * NA + a) * OUTD + ocol;
            if (ATOMIC) unsafeAtomicAdd(&base[off], acc[fm][r]);
            else        base[off] = acc[fm][r];
        }
}

// ---------------------------------------------------------------------------
// Reduce: out = sum of NKS partials (f32x4 vectorized)
// ---------------------------------------------------------------------------
template <int NKS>
__global__ __launch_bounds__(256) void reduce_kernel(const float* __restrict__ P,
                                                     float* __restrict__ out) {
    int i = blockIdx.x * 256 + threadIdx.x;     // 524288 vec4 elems
    f32x4 s = ((const f32x4*)P)[i];
    #pragma unroll
    for (int k = 1; k < NKS; ++k)
        s += ((const f32x4*)(P + (size_t)k * OUT_ELEMS))[i];
    ((f32x4*)out)[i] = s;
}

// ---------------------------------------------------------------------------
// Fallback (ws too small): naive but correct f32 kernel.
// ---------------------------------------------------------------------------
__global__ __launch_bounds__(128) void fallback_kernel(const float* __restrict__ x0,
                                                       const float* __restrict__ x1,
                                                       const float* __restrict__ T,
                                                       float* __restrict__ out) {
    int ba = blockIdx.x;
    int b = ba >> 2, a = ba & 3;
    int o = threadIdx.x;
    const float* h0 = x0 + ((size_t)b * NA + a) * DDIM;
    const float* h1 = x1 + ((size_t)b * NA + a) * DDIM;
    float acc = 0.f;
    for (int i = 0; i < 129; ++i) {
        float h0i = (i < 128) ? h0[i] : 1.f;
        const float* Trow = T + (((size_t)a * 129 + i) * 129) * 128 + o;
        float part = 0.f;
        for (int j = 0; j < 129; ++j) {
            float h1j = (j < 128) ? h1[j] : 1.f;
            part += h1j * Trow[(size_t)j * 128];
        }
        acc += h0i * part;
    }
    out[((size_t)b * NA + a) * OUTD + o] = acc;
}

extern "C" void kernel_launch(void* const* d_in, const int* in_sizes, int n_in,
                              void* d_out, int out_size, void* d_ws, size_t ws_size,
                              hipStream_t stream) {
    const float* x0 = (const float*)d_in[0];
    const float* x1 = (const float*)d_in[1];
    const float* T  = (const float*)d_in[2];
    float* out = (float*)d_out;

    if (ws_size < TB_BYTES) {
        fallback_kernel<<<4096 * NA, 128, 0, stream>>>(x0, x1, T, out);
        return;
    }

    f16* Tb = (f16*)d_ws;
    prep_kernel<<<NA * NTILES, 256, 0, stream>>>(T, Tb);

    if (ws_size >= WS8) {
        // 8-way K-split: 1024 blocks -> 4 blocks/CU, 4 waves/SIMD
        float* P = (float*)((char*)d_ws + TB_BYTES);
        gemm_kernel<8, false><<<1024, 256, 0, stream>>>(x0, x1, Tb, P);
        reduce_kernel<8><<<OUT_ELEMS / 4 / 256, 256, 0, stream>>>(P, out);
    } else if (ws_size >= WS4) {
        // 4-way K-split (round-6 fallback)
        float* P = (float*)((char*)d_ws + TB_BYTES);
        gemm_kernel<4, false><<<512, 256, 0, stream>>>(x0, x1, Tb, P);
        reduce_kernel<4><<<OUT_ELEMS / 4 / 256, 256, 0, stream>>>(P, out);
    } else {
        hipMemsetAsync(d_out, 0, (size_t)out_size * sizeof(float), stream);
        gemm_kernel<4, true><<<512, 256, 0, stream>>>(x0, x1, Tb, out);
    }
}

// Round 9
// 125.311 us; speedup vs baseline: 8.6089x; 8.6089x over previous
//
#include <hip/hip_runtime.h>
#include <stdint.h>
#include <stddef.h>

// Problem: out[b,a,o] = sum_{i,j} h0[b,a,i] h1[b,a,j] T[a,i,j,o], h=concat(x,1)
// GEMM form: C[b,o] += G[b,k]*Tb[a,k,o]; main k=j*128+i (i,j<128); k=16384+c:
// G=h1[c]; k=16512+c: G=h0[c]; k=16640: G=1. 261 K-tiles of 64.
#define NA     4
#define DDIM   128
#define OUTD   128
#define BM     128
#define BN     128
#define NTILES 261
#define TILE_B 16384          // BN * 64 * 2B
#define OUT_ELEMS (4096 * NA * OUTD)   // 2,097,152 f32

typedef _Float16 f16;
typedef __attribute__((ext_vector_type(8)))  _Float16 f16x8;
typedef __attribute__((ext_vector_type(4)))  float    f32x4;
typedef __attribute__((ext_vector_type(16))) float    f32x16;

static const size_t TB_BYTES = (size_t)NA * NTILES * TILE_B;           // 17,104,896
static const size_t WS4 = TB_BYTES + (size_t)4 * OUT_ELEMS * 4;        // ~50.7 MB

typedef const __attribute__((address_space(1))) unsigned int guint_t;
typedef __attribute__((address_space(3))) unsigned int luint_t;

__device__ __forceinline__ void async_copy16(const void* g, void* l) {
    // global -> LDS direct, 16B/lane; LDS dest = wave-uniform base + lane*16
    __builtin_amdgcn_global_load_lds((guint_t*)g, (luint_t*)l, 16, 0, 0);
}

// ---------------------------------------------------------------------------
// Prep: T f32 -> Tb f16, per (a,tile) a 16KB image; unit v = w*128+col
// (w=0..7) holds k = tile*64 + w*8 + e at output-col `col`.
// ---------------------------------------------------------------------------
__global__ __launch_bounds__(256) void prep_kernel(const float* __restrict__ T,
                                                   f16* __restrict__ Tb) {
    int blk  = blockIdx.x;            // a*NTILES + tile
    int a    = blk / NTILES;
    int tile = blk - a * NTILES;
    int t    = threadIdx.x;
    f16* base = Tb + (size_t)blk * (TILE_B / 2);
    #pragma unroll
    for (int u = 0; u < 4; ++u) {
        int v   = t + u * 256;
        int w   = v >> 7;
        int col = v & 127;
        f16x8 ov;
        #pragma unroll
        for (int e = 0; e < 8; ++e) {
            int k = tile * 64 + w * 8 + e;
            int i = -1, j = 0;
            if (k < 16384)       { i = k & 127;   j = k >> 7;    }
            else if (k < 16512)  { i = 128;       j = k - 16384; }
            else if (k < 16640)  { i = k - 16512; j = 128;       }
            else if (k == 16640) { i = 128;       j = 128;       }
            float val = 0.f;
            if (i >= 0) val = T[(((size_t)a * 129 + i) * 129 + j) * 128 + col];
            ov[e] = (f16)val;
        }
        *(f16x8*)(base + (size_t)v * 8) = ov;
    }
}

__device__ __forceinline__ f16x8 pack_f16x8(f32x4 a, f32x4 b) {
    f16x8 h;
    #pragma unroll
    for (int e = 0; e < 4; ++e) { h[e] = (f16)a[e]; h[e + 4] = (f16)b[e]; }
    return h;
}

// One fine-grained phase: 2 ds_read_b128 -> barrier -> lgkm(0) -> prio ->
// 8 MFMA (2 kk-slots x 4 fm, af built in-reg) -> prio -> barrier.
// Stage/vmcnt code is emitted by the caller immediately before the macro
// (i.e. before this phase's first barrier): the vmcnt-before-barrier pair is
// the cross-wave readiness handshake for tile t+1 (m194 discipline).
#define PHASE(BUF, IH, KK)                                                        \
  {                                                                               \
    f16x8 bfa = *(const f16x8*)(&Bs[BUF][(((KK) * 2 + hi) * 128 + wn * 32 + l31) * 16]);       \
    f16x8 bfb = *(const f16x8*)(&Bs[BUF][((((KK) + 1) * 2 + hi) * 128 + wn * 32 + l31) * 16]); \
    __builtin_amdgcn_s_barrier();                                                 \
    asm volatile("s_waitcnt lgkmcnt(0)" ::: "memory");                            \
    __builtin_amdgcn_sched_barrier(0);                                            \
    __builtin_amdgcn_s_setprio(1);                                                \
    _Pragma("unroll")                                                             \
    for (int fm = 0; fm < 4; ++fm) {                                              \
      f16x8 af = h0r[fm][(IH) * 4 + (KK)] * h1v[fm];                              \
      acc[fm] = __builtin_amdgcn_mfma_f32_32x32x16_f16(af, bfa, acc[fm], 0, 0, 0);\
    }                                                                             \
    _Pragma("unroll")                                                             \
    for (int fm = 0; fm < 4; ++fm) {                                              \
      f16x8 af = h0r[fm][(IH) * 4 + (KK) + 1] * h1v[fm];                          \
      acc[fm] = __builtin_amdgcn_mfma_f32_32x32x16_f16(af, bfb, acc[fm], 0, 0, 0);\
    }                                                                             \
    __builtin_amdgcn_s_setprio(0);                                                \
    __builtin_amdgcn_s_barrier();                                                 \
  }

// ---------------------------------------------------------------------------
// GEMM: BM=128 x BN=128, 4 waves (1M x 4N), wave = 128 rows x 32 cols (fm=4).
// B staged global->LDS (4x16KB buffers, 4KB chunks) with the m194-style
// fine-phase schedule: 4 phases per tile-pair, per-phase barrier pair +
// MFMA cluster, counted vmcnt(4) only at tile-end (never 0 in steady state).
// A register-built (h0r resident, h1 scalars from 16KB LDS). NKS=4.
// ---------------------------------------------------------------------------
template <bool ATOMIC>
__global__ __launch_bounds__(256, 2) void gemm_kernel(const float* __restrict__ x0,
                                                      const float* __restrict__ x1,
                                                      const f16* __restrict__ Tb,
                                                      float* __restrict__ dst) {
    __shared__ __align__(16) char Bs[4][TILE_B];    // 64KB B quad-buffer
    __shared__ __align__(16) f16  h1t[64 * 128];    // 16KB h1 window (transposed)

    int bid  = blockIdx.x;
    int xcd  = bid & 7, idx = bid >> 3;
    int pair = xcd * 2 + (idx >> 5);  // (a,ks) pairs contiguous per XCD
    int mt   = idx & 31;
    int a    = pair & 3;
    int ks   = pair >> 2;

    int t    = threadIdx.x;
    int lane = t & 63, wn = t >> 6;          // 4 waves = 4 disjoint N-column sets
    int l31  = lane & 31, hi = lane >> 5;
    int b0   = mt * BM;

    const char* tbb = (const char*)Tb + (size_t)a * NTILES * TILE_B;
    int jbase = ks * 32;
    int jn    = (ks == 0 || ks == 2) ? 64 : 32;
    int ncorr = (ks == 1) ? 2 : 1;

    // chunk c (4KB) of local tile tl -> Bs[buf]; per-wave 1KB slice
    auto stageChunk = [&](int tl, int buf, int c) {
        const char* src = tbb + (size_t)(ks * 64 + tl) * TILE_B + c * 4096 + wn * 1024 + lane * 16;
        char* dstl = &Bs[buf][c * 4096 + wn * 1024];
        async_copy16(src, dstl);
    };

    // ---- one-time h1 window -> LDS (transposed, f16) ----
    {
        int row = t & 127, hs = t >> 7;
        const float* x1r = x1 + ((size_t)(b0 + row) * NA + a) * DDIM + jbase;
        int qn = jn >> 3;                         // 4 or 8 f32x4 loads per thread
        for (int q = hs * qn; q < (hs + 1) * qn; ++q) {
            f32x4 v = *(const f32x4*)(x1r + q * 4);
            #pragma unroll
            for (int e = 0; e < 4; ++e)
                h1t[(q * 4 + e) * 128 + row] = (f16)v[e];
        }
    }
    // ---- one-time h0 -> registers (4 rows/lane, windows split by hi) ----
    f16x8 h0r[4][8];
    #pragma unroll
    for (int fm = 0; fm < 4; ++fm) {
        int row = b0 + fm * 32 + l31;
        const float* x0r = x0 + ((size_t)row * NA + a) * DDIM;
        #pragma unroll
        for (int w = 0; w < 8; ++w) {
            int wf = 2 * w + hi;
            h0r[fm][w] = pack_f16x8(*(const f32x4*)(x0r + wf * 8),
                                    *(const f32x4*)(x0r + wf * 8 + 4));
        }
    }
    __syncthreads();   // h1t visible; all loads drained (clean vmcnt baseline)

    // prologue: stage tiles 0 and 1 (8 chunks outstanding)
    #pragma unroll
    for (int c = 0; c < 4; ++c) stageChunk(0, 0, c);
    #pragma unroll
    for (int c = 0; c < 4; ++c) stageChunk(1, 1, c);
    asm volatile("s_waitcnt vmcnt(4)" ::: "memory");   // own tile-0 chunks landed
    __builtin_amdgcn_s_barrier();                      // tile 0 landed for everyone

    f32x16 acc[4];
    #pragma unroll
    for (int i = 0; i < 4; ++i) acc[i] = (f32x16)0.f;

    // ---- main loop: 32 tile-pairs x 4 phases ----
    #pragma unroll 1
    for (int p = 0; p < 32; ++p) {
        f16 h1v[4];
        #pragma unroll
        for (int fm = 0; fm < 4; ++fm)
            h1v[fm] = h1t[p * 128 + fm * 32 + l31];
        bool more = (p < 31);
        int tA = 2 * p, tB = 2 * p + 1;
        int bufA = tA & 3, bufB = tB & 3;
        int sbufA = (tA + 2) & 3, sbufB = (tB + 2) & 3;

        // tile A (i-half 0)
        if (more) { stageChunk(tA + 2, sbufA, 0); stageChunk(tA + 2, sbufA, 1); }
        PHASE(bufA, 0, 0)
        if (more) { stageChunk(tA + 2, sbufA, 2); stageChunk(tA + 2, sbufA, 3); }
        if (more) asm volatile("s_waitcnt vmcnt(4)" ::: "memory");   // tile tB ready
        else      asm volatile("s_waitcnt vmcnt(0)" ::: "memory");
        PHASE(bufA, 0, 2)

        // tile B (i-half 1)
        if (more) { stageChunk(tB + 2, sbufB, 0); stageChunk(tB + 2, sbufB, 1); }
        PHASE(bufB, 1, 0)
        if (more) { stageChunk(tB + 2, sbufB, 2); stageChunk(tB + 2, sbufB, 3); }
        if (more) asm volatile("s_waitcnt vmcnt(4)" ::: "memory");   // tile tA+2 ready
        PHASE(bufB, 1, 2)
    }

    // ---- correction tail (1-2 tiles, per-ks role), direct global->reg ----
    for (int tt = 0; tt < ncorr; ++tt) {
        int tile;
        if      (ks == 0) tile = 256;
        else if (ks == 1) tile = (tt == 0) ? 258 : 260;
        else if (ks == 2) tile = 257;
        else              tile = 259;
        const char* q = tbb + (size_t)tile * TILE_B + hi * 2048 + (wn * 32 + l31) * 16;
        f16x8 bt[4];
        #pragma unroll
        for (int kk = 0; kk < 4; ++kk) bt[kk] = *(const f16x8*)(q + kk * 4096);

        #pragma unroll
        for (int kk = 0; kk < 4; ++kk) {
            #pragma unroll
            for (int fm = 0; fm < 4; ++fm) {
                int row = fm * 32 + l31;
                f16x8 af;
                if (ks == 0 || ks == 2) {            // j-corr: G = h1[c], c in window
                    #pragma unroll
                    for (int e = 0; e < 8; ++e)
                        af[e] = h1t[(kk * 16 + hi * 8 + e) * 128 + row];
                } else if (ks == 3) {                // i-corr hi: G = h0[64+c]
                    af = h0r[fm][4 + kk];
                } else if (tt == 0) {                // ks==1: i-corr lo: G = h0[c]
                    af = h0r[fm][kk];
                } else {                             // const tile: G = 1 at k_local 0
                    af = (f16x8)(f16)0.f;
                    if (kk == 0 && hi == 0) af[0] = (f16)1.f;
                }
                acc[fm] = __builtin_amdgcn_mfma_f32_32x32x16_f16(af, bt[kk], acc[fm], 0, 0, 0);
            }
        }
    }

    // ---- epilogue: C/D 32x32 layout col=lane&31, row=(r&3)+8*(r>>2)+4*hi ----
    float* base = ATOMIC ? dst : dst + (size_t)ks * OUT_ELEMS;
    #pragma unroll
    for (int fm = 0; fm < 4; ++fm)
        #pragma unroll
        for (int r = 0; r < 16; ++r) {
            int orow = b0 + fm * 32 + (r & 3) + 8 * (r >> 2) + 4 * hi;
            int ocol = wn * 32 + l31;
            size_t off = ((size_t)orow * NA + a) * OUTD + ocol;
            if (ATOMIC) unsafeAtomicAdd(&base[off], acc[fm][r]);
            else        base[off] = acc[fm][r];
        }
}

// ---------------------------------------------------------------------------
// Reduce: out = P0 + P1 + P2 + P3 (f32x4 vectorized)
// ---------------------------------------------------------------------------
__global__ __launch_bounds__(256) void reduce_kernel(const float* __restrict__ P,
                                                     float* __restrict__ out) {
    int i = blockIdx.x * 256 + threadIdx.x;     // 524288 vec4 elems
    f32x4 s = ((const f32x4*)P)[i];
    s += ((const f32x4*)(P + OUT_ELEMS))[i];
    s += ((const f32x4*)(P + 2 * (size_t)OUT_ELEMS))[i];
    s += ((const f32x4*)(P + 3 * (size_t)OUT_ELEMS))[i];
    ((f32x4*)out)[i] = s;
}

// ---------------------------------------------------------------------------
// Fallback (ws too small): naive but correct f32 kernel.
// ---------------------------------------------------------------------------
__global__ __launch_bounds__(128) void fallback_kernel(const float* __restrict__ x0,
                                                       const float* __restrict__ x1,
                                                       const float* __restrict__ T,
                                                       float* __restrict__ out) {
    int ba = blockIdx.x;
    int b = ba >> 2, a = ba & 3;
    int o = threadIdx.x;
    const float* h0 = x0 + ((size_t)b * NA + a) * DDIM;
    const float* h1 = x1 + ((size_t)b * NA + a) * DDIM;
    float acc = 0.f;
    for (int i = 0; i < 129; ++i) {
        float h0i = (i < 128) ? h0[i] : 1.f;
        const float* Trow = T + (((size_t)a * 129 + i) * 129) * 128 + o;
        float part = 0.f;
        for (int j = 0; j < 129; ++j) {
            float h1j = (j < 128) ? h1[j] : 1.f;
            part += h1j * Trow[(size_t)j * 128];
        }
        acc += h0i * part;
    }
    out[((size_t)b * NA + a) * OUTD + o] = acc;
}

extern "C" void kernel_launch(void* const* d_in, const int* in_sizes, int n_in,
                              void* d_out, int out_size, void* d_ws, size_t ws_size,
                              hipStream_t stream) {
    const float* x0 = (const float*)d_in[0];
    const float* x1 = (const float*)d_in[1];
    const float* T  = (const float*)d_in[2];
    float* out = (float*)d_out;

    if (ws_size < TB_BYTES) {
        fallback_kernel<<<4096 * NA, 128, 0, stream>>>(x0, x1, T, out);
        return;
    }

    f16* Tb = (f16*)d_ws;
    prep_kernel<<<NA * NTILES, 256, 0, stream>>>(T, Tb);

    if (ws_size >= WS4) {
        float* P = (float*)((char*)d_ws + TB_BYTES);
        gemm_kernel<false><<<512, 256, 0, stream>>>(x0, x1, Tb, P);
        reduce_kernel<<<OUT_ELEMS / 4 / 256, 256, 0, stream>>>(P, out);
    } else {
        hipMemsetAsync(d_out, 0, (size_t)out_size * sizeof(float), stream);
        gemm_kernel<true><<<512, 256, 0, stream>>>(x0, x1, Tb, out);
    }
}

// Round 10
// 96.544 us; speedup vs baseline: 11.1741x; 1.2980x over previous
//
#include <hip/hip_runtime.h>
#include <stdint.h>
#include <stddef.h>

// Problem: out[b,a,o] = sum_{i,j} h0[b,a,i] h1[b,a,j] T[a,i,j,o], h=concat(x,1)
// GEMM form: C[b,o] += G[b,k]*Tb[a,k,o]; main k=j*128+i (i,j<128); k=16384+c:
// G=h1[c]; k=16512+c: G=h0[c]; k=16640: G=1. 261 K-tiles of 64.
#define NA     4
#define DDIM   128
#define OUTD   128
#define BM     128
#define BN     128
#define NTILES 261
#define TILE_B 16384          // BN * 64 * 2B (16KB per K64-tile image)
#define OUT_ELEMS (4096 * NA * OUTD)   // 2,097,152 f32

typedef _Float16 f16;
typedef __attribute__((ext_vector_type(8)))  _Float16 f16x8;
typedef __attribute__((ext_vector_type(4)))  float    f32x4;

static const size_t TB_BYTES = (size_t)NA * NTILES * TILE_B;           // 17,104,896
static const size_t WS2 = TB_BYTES + (size_t)2 * OUT_ELEMS * 4;        // ~33.9 MB

// ---------------------------------------------------------------------------
// Prep: T f32 -> Tb f16, per (a,tile) a 16KB image; unit v = w*128+col
// (w = k-octet 0..7) holds k = tile*64 + w*8 + e at output-col `col`.
// This [k-octet][col] layout serves BOTH 32x32 and 16x16 fragment reads.
// ---------------------------------------------------------------------------
__global__ __launch_bounds__(256) void prep_kernel(const float* __restrict__ T,
                                                   f16* __restrict__ Tb) {
    int blk  = blockIdx.x;            // a*NTILES + tile
    int a    = blk / NTILES;
    int tile = blk - a * NTILES;
    int t    = threadIdx.x;
    f16* base = Tb + (size_t)blk * (TILE_B / 2);
    #pragma unroll
    for (int u = 0; u < 4; ++u) {
        int v   = t + u * 256;
        int w   = v >> 7;
        int col = v & 127;
        f16x8 ov;
        #pragma unroll
        for (int e = 0; e < 8; ++e) {
            int k = tile * 64 + w * 8 + e;
            int i = -1, j = 0;
            if (k < 16384)       { i = k & 127;   j = k >> 7;    }
            else if (k < 16512)  { i = 128;       j = k - 16384; }
            else if (k < 16640)  { i = k - 16512; j = 128;       }
            else if (k == 16640) { i = 128;       j = 128;       }
            float val = 0.f;
            if (i >= 0) val = T[(((size_t)a * 129 + i) * 129 + j) * 128 + col];
            ov[e] = (f16)val;
        }
        *(f16x8*)(base + (size_t)v * 8) = ov;
    }
}

__device__ __forceinline__ f16x8 pack_f16x8(f32x4 a, f32x4 b) {
    f16x8 h;
    #pragma unroll
    for (int e = 0; e < 4; ++e) { h[e] = (f16)a[e]; h[e + 4] = (f16)b[e]; }
    return h;
}

// ---------------------------------------------------------------------------
// GEMM, round-10 shape experiment: mfma_f32_16x16x32_f16.
// Block: 8 waves (2M x 4N), wave = 64 rows x 32 cols -> acc[4][2] = 8
// independent 4-reg accumulator chains per wave (16/SIMD; was 8/SIMD with
// 32x32 — the hypothesized round-2..9 latency wall). Per iteration (tile
// pair): build ALL 16 A-frags (VALU cluster), then two PURE 16-MFMA bursts.
// B direct global->reg double-buffer, no loop barriers (r6 skeleton).
// NKS=2: grid 256 = 1 block/CU; each XCD streams one (a,ks) 2MB Tb slice.
// ---------------------------------------------------------------------------
template <bool ATOMIC>
__global__ __launch_bounds__(512, 2) void gemm_kernel(const float* __restrict__ x0,
                                                      const float* __restrict__ x1,
                                                      const f16* __restrict__ Tb,
                                                      float* __restrict__ dst) {
    __shared__ __align__(16) f16 h1t[64 * 128];     // 16KB: h1t[j_local*128+row]

    int bid = blockIdx.x;             // 256 blocks = 8 pairs x 32 mt
    int pr  = bid & 7;                // (a,ks) pair, XCD-resident
    int mt  = bid >> 3;
    int a   = pr >> 1;
    int ks  = pr & 1;

    int t    = threadIdx.x;
    int lane = t & 63, wid = t >> 6;
    int wm   = wid >> 2, wn = wid & 3;     // 2M x 4N
    int l15  = lane & 15, g = lane >> 4;   // 16x16 frag: row/col=l15, k-octet=g
    int b0   = mt * BM;

    const char* tbb = (const char*)Tb + (size_t)a * NTILES * TILE_B;

    // ---- one-time h1 window (64 j, base ks*64) -> LDS transposed ----
    {
        int row = t & 127, part = t >> 7;            // 4 parts x 16 j
        const float* x1r = x1 + ((size_t)(b0 + row) * NA + a) * DDIM + ks * 64 + part * 16;
        #pragma unroll
        for (int q = 0; q < 4; ++q) {
            f32x4 v = *(const f32x4*)(x1r + q * 4);
            #pragma unroll
            for (int e = 0; e < 4; ++e)
                h1t[(part * 16 + q * 4 + e) * 128 + row] = (f16)v[e];
        }
    }
    // ---- one-time h0 -> registers: h0r[mf][par][s], window i=par*64+s*32+g*8 ----
    f16x8 h0r[4][2][2];
    #pragma unroll
    for (int mf = 0; mf < 4; ++mf) {
        int row = b0 + wm * 64 + mf * 16 + l15;
        const float* x0r = x0 + ((size_t)row * NA + a) * DDIM;
        #pragma unroll
        for (int par = 0; par < 2; ++par)
            #pragma unroll
            for (int s = 0; s < 2; ++s) {
                int ib = par * 64 + s * 32 + g * 8;
                h0r[mf][par][s] = pack_f16x8(*(const f32x4*)(x0r + ib),
                                             *(const f32x4*)(x0r + ib + 4));
            }
    }
    __syncthreads();   // h1t visible; only barrier in the kernel

    // per-lane B fragment base: frag(nf,s) at ((s*4+g)*128 + wn*32+nf*16+l15)*16
    const char* bp = tbb + (size_t)(ks * 128) * TILE_B + ((size_t)g * 128 + wn * 32 + l15) * 16;
    // flat idx nf*2+s -> byte offset s*8192 + nf*256
    #define BFOFF(nf, s) ((s) * 8192 + (nf) * 256)

    f16x8 bA[4], bB[4];
    #pragma unroll
    for (int nf = 0; nf < 2; ++nf)
        #pragma unroll
        for (int s = 0; s < 2; ++s) {
            bA[nf * 2 + s] = *(const f16x8*)(bp + BFOFF(nf, s));
            bB[nf * 2 + s] = *(const f16x8*)(bp + TILE_B + BFOFF(nf, s));
        }

    f32x4 acc[4][2];
    #pragma unroll
    for (int mf = 0; mf < 4; ++mf)
        #pragma unroll
        for (int nf = 0; nf < 2; ++nf) acc[mf][nf] = (f32x4)0.f;

    // ---- main loop: 64 j's = 64 tile pairs, barrier-free ----
    #pragma unroll 1
    for (int p = 0; p < 64; ++p) {
        // h1 scalars for this j (broadcast LDS reads)
        f16 h1v[4];
        #pragma unroll
        for (int mf = 0; mf < 4; ++mf)
            h1v[mf] = h1t[p * 128 + wm * 64 + mf * 16 + l15];

        // build ALL 16 A-frags up front (pure VALU cluster)
        f16x8 af0[4][2], af1[4][2];
        #pragma unroll
        for (int mf = 0; mf < 4; ++mf)
            #pragma unroll
            for (int s = 0; s < 2; ++s) {
                af0[mf][s] = h0r[mf][0][s] * h1v[mf];
                af1[mf][s] = h0r[mf][1][s] * h1v[mf];
            }

        // tile 2p (par=0): pure 16-MFMA burst; same-acc reuse distance = 8
        #pragma unroll
        for (int s = 0; s < 2; ++s)
            #pragma unroll
            for (int nf = 0; nf < 2; ++nf)
                #pragma unroll
                for (int mf = 0; mf < 4; ++mf)
                    acc[mf][nf] = __builtin_amdgcn_mfma_f32_16x16x32_f16(
                        af0[mf][s], bA[nf * 2 + s], acc[mf][nf], 0, 0, 0);
        {   // prefetch tile 2p+2 into bA
            int nxt = 2 * p + 2; if (nxt > 127) nxt = 127;
            const char* q = bp + (size_t)nxt * TILE_B;
            #pragma unroll
            for (int nf = 0; nf < 2; ++nf)
                #pragma unroll
                for (int s = 0; s < 2; ++s)
                    bA[nf * 2 + s] = *(const f16x8*)(q + BFOFF(nf, s));
        }
        // tile 2p+1 (par=1): pure 16-MFMA burst
        #pragma unroll
        for (int s = 0; s < 2; ++s)
            #pragma unroll
            for (int nf = 0; nf < 2; ++nf)
                #pragma unroll
                for (int mf = 0; mf < 4; ++mf)
                    acc[mf][nf] = __builtin_amdgcn_mfma_f32_16x16x32_f16(
                        af1[mf][s], bB[nf * 2 + s], acc[mf][nf], 0, 0, 0);
        {   // prefetch tile 2p+3 into bB
            int nxt = 2 * p + 3; if (nxt > 127) nxt = 127;
            const char* q = bp + (size_t)nxt * TILE_B;
            #pragma unroll
            for (int nf = 0; nf < 2; ++nf)
                #pragma unroll
                for (int s = 0; s < 2; ++s)
                    bB[nf * 2 + s] = *(const f16x8*)(q + BFOFF(nf, s));
        }
    }

    // ---- correction tail: ks0 -> {256 j-corr lo, 258 i-corr lo};
    //                        ks1 -> {257 j-corr hi, 259 i-corr hi, 260 const}
    int ncorr = (ks == 0) ? 2 : 3;
    for (int tt = 0; tt < ncorr; ++tt) {
        int tile = (ks == 0) ? ((tt == 0) ? 256 : 258)
                             : ((tt == 0) ? 257 : (tt == 1) ? 259 : 260);
        const char* q = tbb + (size_t)tile * TILE_B + ((size_t)g * 128 + wn * 32 + l15) * 16;
        f16x8 bt[4];
        #pragma unroll
        for (int nf = 0; nf < 2; ++nf)
            #pragma unroll
            for (int s = 0; s < 2; ++s)
                bt[nf * 2 + s] = *(const f16x8*)(q + BFOFF(nf, s));

        #pragma unroll
        for (int s = 0; s < 2; ++s)
            #pragma unroll
            for (int mf = 0; mf < 4; ++mf) {
                int row = wm * 64 + mf * 16 + l15;
                f16x8 af;
                if (tile == 256 || tile == 257) {        // j-corr: G=h1[c], window-local
                    #pragma unroll
                    for (int e = 0; e < 8; ++e)
                        af[e] = h1t[(s * 32 + g * 8 + e) * 128 + row];
                } else if (tile == 258) {                // i-corr lo: G=h0[c], par0
                    af = h0r[mf][0][s];
                } else if (tile == 259) {                // i-corr hi: par1
                    af = h0r[mf][1][s];
                } else {                                 // 260: G=1 at k_local 0
                    af = (f16x8)(f16)0.f;
                    if (s == 0 && g == 0) af[0] = (f16)1.f;
                }
                #pragma unroll
                for (int nf = 0; nf < 2; ++nf)
                    acc[mf][nf] = __builtin_amdgcn_mfma_f32_16x16x32_f16(
                        af, bt[nf * 2 + s], acc[mf][nf], 0, 0, 0);
            }
    }

    // ---- epilogue: 16x16 C/D layout col=lane&15, row=(lane>>4)*4+r (verified) ----
    float* base = ATOMIC ? dst : dst + (size_t)ks * OUT_ELEMS;
    #pragma unroll
    for (int mf = 0; mf < 4; ++mf)
        #pragma unroll
        for (int nf = 0; nf < 2; ++nf)
            #pragma unroll
            for (int r = 0; r < 4; ++r) {
                int orow = b0 + wm * 64 + mf * 16 + g * 4 + r;
                int ocol = wn * 32 + nf * 16 + l15;
                size_t off = ((size_t)orow * NA + a) * OUTD + ocol;
                if (ATOMIC) unsafeAtomicAdd(&base[off], acc[mf][nf][r]);
                else        base[off] = acc[mf][nf][r];
            }
    #undef BFOFF
}

// ---------------------------------------------------------------------------
// Reduce: out = P0 + P1 (f32x4 vectorized)
// ---------------------------------------------------------------------------
__global__ __launch_bounds__(256) void reduce_kernel(const float* __restrict__ P,
                                                     float* __restrict__ out) {
    int i = blockIdx.x * 256 + threadIdx.x;     // 524288 vec4 elems
    f32x4 s = ((const f32x4*)P)[i];
    s += ((const f32x4*)(P + OUT_ELEMS))[i];
    ((f32x4*)out)[i] = s;
}

// ---------------------------------------------------------------------------
// Fallback (ws too small): naive but correct f32 kernel.
// ---------------------------------------------------------------------------
__global__ __launch_bounds__(128) void fallback_kernel(const float* __restrict__ x0,
                                                       const float* __restrict__ x1,
                                                       const float* __restrict__ T,
                                                       float* __restrict__ out) {
    int ba = blockIdx.x;
    int b = ba >> 2, a = ba & 3;
    int o = threadIdx.x;
    const float* h0 = x0 + ((size_t)b * NA + a) * DDIM;
    const float* h1 = x1 + ((size_t)b * NA + a) * DDIM;
    float acc = 0.f;
    for (int i = 0; i < 129; ++i) {
        float h0i = (i < 128) ? h0[i] : 1.f;
        const float* Trow = T + (((size_t)a * 129 + i) * 129) * 128 + o;
        float part = 0.f;
        for (int j = 0; j < 129; ++j) {
            float h1j = (j < 128) ? h1[j] : 1.f;
            part += h1j * Trow[(size_t)j * 128];
        }
        acc += h0i * part;
    }
    out[((size_t)b * NA + a) * OUTD + o] = acc;
}

extern "C" void kernel_launch(void* const* d_in, const int* in_sizes, int n_in,
                              void* d_out, int out_size, void* d_ws, size_t ws_size,
                              hipStream_t stream) {
    const float* x0 = (const float*)d_in[0];
    const float* x1 = (const float*)d_in[1];
    const float* T  = (const float*)d_in[2];
    float* out = (float*)d_out;

    if (ws_size < TB_BYTES) {
        fallback_kernel<<<4096 * NA, 128, 0, stream>>>(x0, x1, T, out);
        return;
    }

    f16* Tb = (f16*)d_ws;
    prep_kernel<<<NA * NTILES, 256, 0, stream>>>(T, Tb);

    if (ws_size >= WS2) {
        float* P = (float*)((char*)d_ws + TB_BYTES);
        gemm_kernel<false><<<256, 512, 0, stream>>>(x0, x1, Tb, P);
        reduce_kernel<<<OUT_ELEMS / 4 / 256, 256, 0, stream>>>(P, out);
    } else {
        hipMemsetAsync(d_out, 0, (size_t)out_size * sizeof(float), stream);
        gemm_kernel<true><<<256, 512, 0, stream>>>(x0, x1, Tb, out);
    }
}